// Round 11
// baseline (134.855 us; speedup 1.0000x reference)
//
#include <hip/hip_runtime.h>
#include <hip/hip_bf16.h>

// B=8, T=2048, C=1024, H=64 single-head causal attention. f32 in, f32 out.
// Round 20: qkv 2-blocks/CU. R5/R7/R10 all failed to overlap stage+compute
// INSIDE one barrier-locked block (barriers idle all waves together). New
// shape gives the CU two INDEPENDENT blocks: M=32, 384 thr (6 waves), grid
// 512, LDS 64 KB -> exactly 2 blocks/CU (12 waves = 3/SIMD, VGPR<=128).
// Wave owns 2 fragment-cols x 2 row-groups (4 MFMA/kci, wf ring [2][2]).
// Wp read once per block = 768 KB/CU CONTIGUOUS (packed layout keeps the
// per-KB cost ~3x below the old strided tax; the +384 KB is the known ~3us
// price paid for cross-block overlap). Staging depth unchanged (21 loads/
// thread, groups of 7); [kci][row][quad] LDS slabs halved to 2048B.
// attn/transpose_w byte-identical to R18/R9 (best, 130.05us).
// fillBufferAligned (2x ~41us, 268MB ws-poison) = unconditional fixed floor.
// Region map: region rt (0..1023) = 16 tokens, stride regsz bf16.
// Q[t][h]@0, K packed@1024 (2 half-frags), V^T[h][t16]@2048.

typedef __bf16 bf16;
typedef __bf16 bf16x8 __attribute__((ext_vector_type(8)));
typedef float f32x4 __attribute__((ext_vector_type(4)));
typedef unsigned int u32;
typedef u32 u32x2 __attribute__((ext_vector_type(2)));
typedef u32 u32x4 __attribute__((ext_vector_type(4)));

#define T_SZ 2048
#define C_SZ 1024
#define H_SZ 64
#define QOFF 0
#define KOFF 1024
#define VOFF 2048
#define PPITCH 72
#define NEG_BIG (-30000.0f)
#define QSCALE 0.04508422f  // (1/32) * log2(e)

__device__ __forceinline__ bf16x8 ld8(const bf16* p) { return *(const bf16x8*)p; }

// DPP rotate within 16-lane row. ROW_ROR:n = 0x120|n.
template <int CTRL>
__device__ __forceinline__ float dpp_mov(float x) {
  return __builtin_bit_cast(float,
      __builtin_amdgcn_update_dpp(0, __builtin_bit_cast(int, x), CTRL, 0xf, 0xf, true));
}
__device__ __forceinline__ float qmax16(float x) {
  x = fmaxf(x, dpp_mov<0x121>(x));
  x = fmaxf(x, dpp_mov<0x122>(x));
  x = fmaxf(x, dpp_mov<0x124>(x));
  x = fmaxf(x, dpp_mov<0x128>(x));
  return x;
}
__device__ __forceinline__ float qsum16(float x) {
  x += dpp_mov<0x121>(x);
  x += dpp_mov<0x122>(x);
  x += dpp_mov<0x124>(x);
  x += dpp_mov<0x128>(x);
  return x;
}

// ---------------------------------------------------------------------------
// Fragment-packed weights: Wp elem[(jj*32+kci)*512 + l15*32 + quad*8 + e] =
// W[c = kci*32+quad*8+e][h = (jj&3)*16+l15] of matrix jj>>2 (0=Q,1=K,2=V).
// QSCALE folded into Wq. Thread (r=h, cb) covers c = ct*64+cb .. +15.
__global__ __launch_bounds__(256) void transpose_w(const float* __restrict__ Wq,
                                                   const float* __restrict__ Wk,
                                                   const float* __restrict__ Wv,
                                                   bf16* __restrict__ Wp) {
  __shared__ float sh[64][65];
  int ct = blockIdx.x;
  int mat = blockIdx.y;
  const float* W = (mat == 0) ? Wq : (mat == 1 ? Wk : Wv);
  int tid = threadIdx.x;
  int r = tid >> 2, cb = (tid & 3) * 16;

  const f32x4* src = (const f32x4*)(W + (size_t)(ct * 64 + r) * H_SZ + cb);
#pragma unroll
  for (int v = 0; v < 4; ++v) {
    f32x4 x = src[v];
#pragma unroll
    for (int jx = 0; jx < 4; ++jx) sh[r][cb + v * 4 + jx] = x[jx];
  }
  __syncthreads();

  float scale = (mat == 0) ? QSCALE : 1.0f;
  bf16x8 o0, o1;
#pragma unroll
  for (int jx = 0; jx < 8; ++jx) o0[jx] = (bf16)(sh[cb + jx][r] * scale);
#pragma unroll
  for (int jx = 0; jx < 8; ++jx) o1[jx] = (bf16)(sh[cb + 8 + jx][r] * scale);

  int jj = mat * 4 + (r >> 4);       // fragment-col 0..11
  int l15 = r & 15;
  int c0 = ct * 64 + cb;
  int kci = c0 >> 5;
  int qa = (c0 >> 3) & 3;            // first quad of the 16-elem span
  bf16* dst = Wp + (size_t)(jj * 32 + kci) * 512 + l15 * 32 + qa * 8;
  *(bf16x8*)dst = o0;        // quad qa   (8 elems)
  *(bf16x8*)(dst + 8) = o1;  // quad qa+1 (8 elems)
}

// ---------------------------------------------------------------------------
// QKV: 512 blocks x 384 thr (6 waves), 2 blocks/CU, M=32 tokens.
// Wave w owns fragment-cols j0=2w, j0+1 (w<4 -> Q/K, else V) and feeds each
// to 2 MFMAs (row-groups rg=0,1) per kci. Wp read once per block; every wf
// load contiguous 1KB (packed layout). LDS: [kci][row][quad], slab 2048B,
// 64KB total -> 2 blocks/CU; df reads 1024B-contiguous, conflict-free.
// Cross-block overlap: while one block sits at its barrier / drains loads,
// the other block's waves issue MFMAs — the overlap R5/R7/R10 couldn't get
// inside a single barrier-locked block.
//   Q/K: mfma(wf, df) -> D[h][t];  V: mfma(df, wf) -> D[t][h].
// K epilogue stores in half-fragment order for attn's contiguous kf loads.
__global__ __launch_bounds__(384, 3) void qkv(const float* data, const bf16* __restrict__ Wp,
                                              bf16* arena, int regsz) {
  __shared__ bf16 As[32 * 1024];  // 64 KiB, tiled addressing via bytes
  char* As_b = (char*)As;
  int blk = blockIdx.x;
  int tid = threadIdx.x;
  int w = tid >> 6, lane = tid & 63;
  int l15 = lane & 15, quad = lane >> 4;

  // ---- stage 32 rows x 1024 f32 -> bf16 LDS (nontemporal, full coverage) --
  // 8192 f32x4 units = 21*384 + 128 tail.
  const float* src = data + (size_t)blk * 32 * C_SZ;
#pragma unroll
  for (int g = 0; g < 3; ++g) {
    f32x4 st[7];
#pragma unroll
    for (int i = 0; i < 7; ++i) {
      int u = (g * 7 + i) * 384 + tid;  // u < 8064 = rows 0..31
      st[i] = __builtin_nontemporal_load(
          (const f32x4*)(src + (size_t)(u >> 8) * C_SZ + (u & 255) * 4));
    }
#pragma unroll
    for (int i = 0; i < 7; ++i) {
      int u = (g * 7 + i) * 384 + tid;
      int row = u >> 8, c4 = u & 255;
      bf16 t4[4] = {(bf16)st[i][0], (bf16)st[i][1], (bf16)st[i][2], (bf16)st[i][3]};
      int bo = ((c4 >> 3) << 11) + row * 64 + (c4 & 7) * 8;
      *(u32x2*)(As_b + bo) = *(const u32x2*)t4;
    }
  }
  if (tid < 128) {  // tail units 8064..8191 (last half of row 31)
    int u = 8064 + tid;
    int row = u >> 8, c4 = u & 255;
    f32x4 x = __builtin_nontemporal_load(
        (const f32x4*)(src + (size_t)row * C_SZ + c4 * 4));
    bf16 t4[4] = {(bf16)x[0], (bf16)x[1], (bf16)x[2], (bf16)x[3]};
    int bo = ((c4 >> 3) << 11) + row * 64 + (c4 & 7) * 8;
    *(u32x2*)(As_b + bo) = *(const u32x2*)t4;
  }
  __syncthreads();

  // ---- compute: wave w owns fragment-cols j0 = 2w, j0+1 -------------------
  int j0 = 2 * w;
  const bf16* wb0 = Wp + (size_t)j0 * 32 * 512 + l15 * 32 + quad * 8;  // kci stride 512
  const bf16* wb1 = wb0 + 32 * 512;
  bf16x8 wf0[2], wf1[2];
  wf0[0] = ld8(wb0);        // kci 0
  wf0[1] = ld8(wb0 + 512);  // kci 1
  wf1[0] = ld8(wb1);
  wf1[1] = ld8(wb1 + 512);

  f32x4 acc[2][2];  // [jc][rg]
  f32x4 zero = {0.f, 0.f, 0.f, 0.f};
#pragma unroll
  for (int jc = 0; jc < 2; ++jc)
#pragma unroll
    for (int rg = 0; rg < 2; ++rg) acc[jc][rg] = zero;

  bool isQK = (j0 < 8);  // uniform per wave (both cols same class)
  int lbase = l15 * 64 + quad * 16;  // lane offset within a 1024B (kci,rg) slab

#pragma unroll 2
  for (int kci = 0; kci < 32; ++kci) {
    int cur = kci & 1;  // compile-time under unroll 2
    bf16x8 df[2];
#pragma unroll
    for (int rg = 0; rg < 2; ++rg)
      df[rg] = ld8((const bf16*)(As_b + (kci << 11) + rg * 1024 + lbase));
    if (isQK) {
      acc[0][0] = __builtin_amdgcn_mfma_f32_16x16x32_bf16(wf0[cur], df[0], acc[0][0], 0, 0, 0);
      acc[0][1] = __builtin_amdgcn_mfma_f32_16x16x32_bf16(wf0[cur], df[1], acc[0][1], 0, 0, 0);
      acc[1][0] = __builtin_amdgcn_mfma_f32_16x16x32_bf16(wf1[cur], df[0], acc[1][0], 0, 0, 0);
      acc[1][1] = __builtin_amdgcn_mfma_f32_16x16x32_bf16(wf1[cur], df[1], acc[1][1], 0, 0, 0);
    } else {
      acc[0][0] = __builtin_amdgcn_mfma_f32_16x16x32_bf16(df[0], wf0[cur], acc[0][0], 0, 0, 0);
      acc[0][1] = __builtin_amdgcn_mfma_f32_16x16x32_bf16(df[1], wf0[cur], acc[0][1], 0, 0, 0);
      acc[1][0] = __builtin_amdgcn_mfma_f32_16x16x32_bf16(df[0], wf1[cur], acc[1][0], 0, 0, 0);
      acc[1][1] = __builtin_amdgcn_mfma_f32_16x16x32_bf16(df[1], wf1[cur], acc[1][1], 0, 0, 0);
    }
    int knx = ((kci + 2) & 31) * 512;  // refill for kci+2 (wrap-safe)
    wf0[cur] = ld8(wb0 + knx);
    wf1[cur] = ld8(wb1 + knx);
  }

  // ---- epilogue: packed 8B stores into 2 sub-regions ----------------------
#pragma unroll
  for (int jc = 0; jc < 2; ++jc) {
    int j = j0 + jc;
#pragma unroll
    for (int rg = 0; rg < 2; ++rg) {
      bf16* reg = arena + (size_t)(blk * 2 + rg) * (size_t)regsz;
      bf16 p4[4] = {(bf16)acc[jc][rg][0], (bf16)acc[jc][rg][1],
                    (bf16)acc[jc][rg][2], (bf16)acc[jc][rg][3]};
      if (j < 4) {         // Q: [t][h], t=l15, h = j*16 + quad*4 + r
        bf16* dst = reg + QOFF + l15 * 64 + j * 16 + quad * 4;
        *(u32x2*)dst = *(const u32x2*)p4;
      } else if (j < 8) {  // K: half-fragment order, h = (j-4)*16 + quad*4 + r
        int jk = j - 4;
        bf16* dst = reg + KOFF + (jk >> 1) * 512 + l15 * 32 + (jk & 1) * 16 + quad * 4;
        *(u32x2*)dst = *(const u32x2*)p4;
      } else {             // V: D[t][h] -> V^T[h][t16], h = (j-8)*16 + l15
        bf16* dst = reg + VOFF + ((j - 8) * 16 + l15) * 16 + quad * 4;
        *(u32x2*)dst = *(const u32x2*)p4;
      }
    }
  }
}

// ---------------------------------------------------------------------------
// Flash attention. Block = one (qt, slice, b) 16x64 output tile; 4 waves each
// own a QUARTER of kt in [0, qt], private (m,l,accO); one LDS merge at end.
// Grid 1024 1-D: b = id&7 (pins batch b to XCD b), t = id>>3, slice = t&3,
// qt = 31-(t>>2) (LPT order). 4 blocks/CU -> 16 waves/CU.
// K is stored in half-fragment order: kf loads are contiguous 1KB blocks.
__global__ __launch_bounds__(256, 4) void attn(const bf16* __restrict__ arena,
                                               float* __restrict__ out, int regsz) {
  __shared__ bf16 Ps[4][16 * PPITCH];
  __shared__ f32x4 Mg[3][6][64];  // waves 1..3 dump {accO[0..3], m, l}
  int id = blockIdx.x;
  int b = id & 7;
  int t = id >> 3;
  int slice = t & 3;
  int qt = 31 - (t >> 2);
  int tid = threadIdx.x;
  int w = tid >> 6, lane = tid & 63;
  int l15 = lane & 15, quad = lane >> 4;

  const bf16* base = arena + (size_t)b * 128 * (size_t)regsz;

  const bf16* qreg = base + (size_t)(qt * 4 + slice) * (size_t)regsz + QOFF + l15 * 64;
  bf16x8 qf0 = ld8(qreg + quad * 8);
  bf16x8 qf1 = ld8(qreg + 32 + quad * 8);

  f32x4 accO[4];
  f32x4 zero = {0.f, 0.f, 0.f, 0.f};
#pragma unroll
  for (int nt = 0; nt < 4; ++nt) accO[nt] = zero;
  float m[4], l[4];
#pragma unroll
  for (int r = 0; r < 4; ++r) { m[r] = NEG_BIG; l[r] = 0.f; }

  int qrow_base = qt * 64 + slice * 16 + quad * 4;
  int vro = (quad >> 1);                 // V region sub-index
  int vco = (quad & 1) * 8;              // V in-row offset

  // this wave's kt quarter
  int q4 = (qt + 4) >> 2;                // ceil((qt+1)/4)
  int kbeg = w * q4;
  int kend = min((w + 1) * q4, qt + 1);  // may be empty (kbeg >= kend)

  for (int kt = kbeg; kt < kend; ++kt) {
    // K fragments for this tile (contiguous 1KB half-fragments)
    bf16x8 kf[8];
#pragma unroll
    for (int nt = 0; nt < 4; ++nt) {
      const bf16* kp = base + (size_t)(kt * 4 + nt) * (size_t)regsz + KOFF + l15 * 32 + quad * 8;
      kf[2 * nt] = ld8(kp);            // h 0..31 half
      kf[2 * nt + 1] = ld8(kp + 512);  // h 32..63 half
    }

    f32x4 sA[4];
#pragma unroll
    for (int nt = 0; nt < 4; ++nt) sA[nt] = zero;
#pragma unroll
    for (int nt = 0; nt < 4; ++nt) {
      sA[nt] = __builtin_amdgcn_mfma_f32_16x16x32_bf16(qf0, kf[2 * nt], sA[nt], 0, 0, 0);
      sA[nt] = __builtin_amdgcn_mfma_f32_16x16x32_bf16(qf1, kf[2 * nt + 1], sA[nt], 0, 0, 0);
    }

    // first V half: issue under the softmax (kf regs die at the MFMAs above)
    bf16x8 vf0[4];
#pragma unroll
    for (int nt = 0; nt < 4; ++nt) {
      const bf16* vp = base + (size_t)(kt * 4 + vro) * (size_t)regsz + VOFF +
                       (nt * 16 + l15) * 16 + vco;
      vf0[nt] = ld8(vp);
    }

    if (kt == qt) {  // causal mask on diagonal tile
#pragma unroll
      for (int nt = 0; nt < 4; ++nt) {
        int colg = kt * 64 + nt * 16 + l15;
#pragma unroll
        for (int r = 0; r < 4; ++r)
          if (colg > qrow_base + r) sA[nt][r] = NEG_BIG;
      }
    }

    float alpha[4];
#pragma unroll
    for (int r = 0; r < 4; ++r) {
      float mx = qmax16(fmaxf(fmaxf(sA[0][r], sA[1][r]), fmaxf(sA[2][r], sA[3][r])));
      float mnew = fmaxf(m[r], mx);
      alpha[r] = exp2f(m[r] - mnew);
      m[r] = mnew;
    }

    float rs[4] = {0.f, 0.f, 0.f, 0.f};
#pragma unroll
    for (int nt = 0; nt < 4; ++nt) {
#pragma unroll
      for (int r = 0; r < 4; ++r) {
        float p = exp2f(sA[nt][r] - m[r]);
        sA[nt][r] = p;
        rs[r] += p;
      }
    }
#pragma unroll
    for (int r = 0; r < 4; ++r) l[r] = l[r] * alpha[r] + qsum16(rs[r]);

    // P: C/D layout -> per-wave LDS -> A layout (same-wave RAW, lgkm-ordered)
#pragma unroll
    for (int nt = 0; nt < 4; ++nt) {
#pragma unroll
      for (int r = 0; r < 4; ++r)
        Ps[w][(quad * 4 + r) * PPITCH + nt * 16 + l15] = (bf16)sA[nt][r];
    }

    // second V half: issue before PV so latency hides under first PV block
    bf16x8 vf1[4];
#pragma unroll
    for (int nt = 0; nt < 4; ++nt) {
      const bf16* vp = base + (size_t)(kt * 4 + 2 + vro) * (size_t)regsz + VOFF +
                       (nt * 16 + l15) * 16 + vco;
      vf1[nt] = ld8(vp);
    }

#pragma unroll
    for (int nt = 0; nt < 4; ++nt) {
#pragma unroll
      for (int r = 0; r < 4; ++r) accO[nt][r] *= alpha[r];
    }
    bf16x8 pf0 = ld8((const bf16*)Ps[w] + l15 * PPITCH + quad * 8);
    bf16x8 pf1 = ld8((const bf16*)Ps[w] + l15 * PPITCH + 32 + quad * 8);
#pragma unroll
    for (int nt = 0; nt < 4; ++nt)
      accO[nt] = __builtin_amdgcn_mfma_f32_16x16x32_bf16(pf0, vf0[nt], accO[nt], 0, 0, 0);
#pragma unroll
    for (int nt = 0; nt < 4; ++nt)
      accO[nt] = __builtin_amdgcn_mfma_f32_16x16x32_bf16(pf1, vf1[nt], accO[nt], 0, 0, 0);
  }

  // merge the 4 kt-quarter partials (exact: O* = sum_w O_w * 2^(m_w - m*))
  if (w > 0) {
#pragma unroll
    for (int nt = 0; nt < 4; ++nt) Mg[w - 1][nt][lane] = accO[nt];
    f32x4 mv = {m[0], m[1], m[2], m[3]};
    f32x4 lv = {l[0], l[1], l[2], l[3]};
    Mg[w - 1][4][lane] = mv;
    Mg[w - 1][5][lane] = lv;
  }
  __syncthreads();
  if (w == 0) {
#pragma unroll
    for (int wv = 0; wv < 3; ++wv) {
      f32x4 mo = Mg[wv][4][lane];
      f32x4 lo = Mg[wv][5][lane];
      f32x4 oo[4];
#pragma unroll
      for (int nt = 0; nt < 4; ++nt) oo[nt] = Mg[wv][nt][lane];
#pragma unroll
      for (int r = 0; r < 4; ++r) {
        float mnew = fmaxf(m[r], mo[r]);
        float a = exp2f(m[r] - mnew);
        float bs = exp2f(mo[r] - mnew);
        l[r] = l[r] * a + lo[r] * bs;
#pragma unroll
        for (int nt = 0; nt < 4; ++nt) accO[nt][r] = accO[nt][r] * a + oo[nt][r] * bs;
        m[r] = mnew;
      }
    }

    float inv[4];
#pragma unroll
    for (int r = 0; r < 4; ++r) inv[r] = 1.f / l[r];
#pragma unroll
    for (int nt = 0; nt < 4; ++nt) {
#pragma unroll
      for (int r = 0; r < 4; ++r) {
        int tk = qt * 64 + slice * 16 + quad * 4 + r;
        int h = nt * 16 + l15;
        out[((size_t)b * T_SZ + tk) * H_SZ + h] = accO[nt][r] * inv[r];
      }
    }
  }
}

// ---------------------------------------------------------------------------
extern "C" void kernel_launch(void* const* d_in, const int* in_sizes, int n_in,
                              void* d_out, int out_size, void* d_ws, size_t ws_size,
                              hipStream_t stream) {
  const float* data = (const float*)d_in[0];

  // Preferred: arena (1024 regions x 4096 bf16 = 8 MB) + Wp (384 KB) in d_ws.
  // Fallback (tiny ws): alias input (stride 32768) + Wp in d_out. Each M=32
  // qkv block fully consumes its own 128 KB input before writing its two
  // 16-token regions (which lie inside that same span).
  const size_t arena_bytes = (size_t)1024 * 4096 * sizeof(bf16);  // 8 MB
  const size_t wt_bytes = (size_t)3 * H_SZ * C_SZ * sizeof(bf16); // 384 KB
  bool ws_ok = (d_ws != nullptr) && (ws_size >= arena_bytes + wt_bytes);

  bf16* arena = ws_ok ? (bf16*)d_ws : (bf16*)d_in[0];
  bf16* Wp = ws_ok ? (bf16*)((char*)d_ws + arena_bytes) : (bf16*)d_out;
  int regsz = ws_ok ? 4096 : 32768;

  transpose_w<<<dim3(16, 3), 256, 0, stream>>>((const float*)d_in[1],
                                               (const float*)d_in[2],
                                               (const float*)d_in[3], Wp);
  qkv<<<512, 384, 0, stream>>>(data, Wp, arena, regsz);
  attn<<<1024, 256, 0, stream>>>(arena, (float*)d_out, regsz);
}

// Round 12
// 132.386 us; speedup vs baseline: 1.0187x; 1.0187x over previous
//
#include <hip/hip_runtime.h>
#include <hip/hip_bf16.h>

// B=8, T=2048, C=1024, H=64 single-head causal attention. f32 in, f32 out.
// Round 21: qkv/transpose_w reverted byte-for-byte to R9 (best, 130.05us;
// R5/R7/R10/R11 all failed to beat its serial stage+compute — family closed).
// attn rebuilt for L2-traffic: each wave now covers 32 q-rows (two 16-row
// slices) per loaded K/V tile, halving wave-tiles (16896 -> 8448) and K/V L2
// reads (270 -> 135 MB, ~8 -> ~4us floor). Block = (qt, sp, b), grid 512,
// launch_bounds(256,2) (VGPR cap 256, est ~190 live, 8 waves/CU).
// Freebies: next tile's K loads into the SAME kf regs after QK (zero-cost
// prefetch, hidden under softmax+PV); dispatch map qt = u<32 ? 31-(u>>1) :
// (u-32)>>1 makes each CU's two blocks sum to exactly 33 kt-tiles.
// fillBufferAligned (2x ~41us ws-poison) = unconditional harness floor.
// Region map: region rt (0..1023) = 16 tokens, stride regsz bf16.
// Q[t][h]@0, K packed@1024 (2 half-frags), V^T[h][t16]@2048.

typedef __bf16 bf16;
typedef __bf16 bf16x8 __attribute__((ext_vector_type(8)));
typedef float f32x4 __attribute__((ext_vector_type(4)));
typedef unsigned int u32;
typedef u32 u32x2 __attribute__((ext_vector_type(2)));
typedef u32 u32x4 __attribute__((ext_vector_type(4)));

#define T_SZ 2048
#define C_SZ 1024
#define H_SZ 64
#define QOFF 0
#define KOFF 1024
#define VOFF 2048
#define PPITCH 72
#define NEG_BIG (-30000.0f)
#define QSCALE 0.04508422f  // (1/32) * log2(e)

__device__ __forceinline__ bf16x8 ld8(const bf16* p) { return *(const bf16x8*)p; }

// DPP rotate within 16-lane row. ROW_ROR:n = 0x120|n.
template <int CTRL>
__device__ __forceinline__ float dpp_mov(float x) {
  return __builtin_bit_cast(float,
      __builtin_amdgcn_update_dpp(0, __builtin_bit_cast(int, x), CTRL, 0xf, 0xf, true));
}
__device__ __forceinline__ float qmax16(float x) {
  x = fmaxf(x, dpp_mov<0x121>(x));
  x = fmaxf(x, dpp_mov<0x122>(x));
  x = fmaxf(x, dpp_mov<0x124>(x));
  x = fmaxf(x, dpp_mov<0x128>(x));
  return x;
}
__device__ __forceinline__ float qsum16(float x) {
  x += dpp_mov<0x121>(x);
  x += dpp_mov<0x122>(x);
  x += dpp_mov<0x124>(x);
  x += dpp_mov<0x128>(x);
  return x;
}

// ---------------------------------------------------------------------------
// Fragment-packed weights: Wp elem[(jj*32+kci)*512 + l15*32 + quad*8 + e] =
// W[c = kci*32+quad*8+e][h = (jj&3)*16+l15] of matrix jj>>2 (0=Q,1=K,2=V).
// QSCALE folded into Wq. Thread (r=h, cb) covers c = ct*64+cb .. +15.
__global__ __launch_bounds__(256) void transpose_w(const float* __restrict__ Wq,
                                                   const float* __restrict__ Wk,
                                                   const float* __restrict__ Wv,
                                                   bf16* __restrict__ Wp) {
  __shared__ float sh[64][65];
  int ct = blockIdx.x;
  int mat = blockIdx.y;
  const float* W = (mat == 0) ? Wq : (mat == 1 ? Wk : Wv);
  int tid = threadIdx.x;
  int r = tid >> 2, cb = (tid & 3) * 16;

  const f32x4* src = (const f32x4*)(W + (size_t)(ct * 64 + r) * H_SZ + cb);
#pragma unroll
  for (int v = 0; v < 4; ++v) {
    f32x4 x = src[v];
#pragma unroll
    for (int jx = 0; jx < 4; ++jx) sh[r][cb + v * 4 + jx] = x[jx];
  }
  __syncthreads();

  float scale = (mat == 0) ? QSCALE : 1.0f;
  bf16x8 o0, o1;
#pragma unroll
  for (int jx = 0; jx < 8; ++jx) o0[jx] = (bf16)(sh[cb + jx][r] * scale);
#pragma unroll
  for (int jx = 0; jx < 8; ++jx) o1[jx] = (bf16)(sh[cb + 8 + jx][r] * scale);

  int jj = mat * 4 + (r >> 4);       // fragment-col 0..11
  int l15 = r & 15;
  int c0 = ct * 64 + cb;
  int kci = c0 >> 5;
  int qa = (c0 >> 3) & 3;            // first quad of the 16-elem span
  bf16* dst = Wp + (size_t)(jj * 32 + kci) * 512 + l15 * 32 + qa * 8;
  *(bf16x8*)dst = o0;        // quad qa   (8 elems)
  *(bf16x8*)(dst + 8) = o1;  // quad qa+1 (8 elems)
}

// ---------------------------------------------------------------------------
// QKV (R9 verbatim): 256 blocks x 768 thr (12 waves), 1 block/CU, M=64.
// Wave j (0..11) owns ONE 16-col fragment (j<4 Q, j<8 K, else V) and feeds
// it to 4 MFMAs (row-groups) per kci. Wp traffic 384 KB/CU, every wf load
// contiguous 1KB. LDS: tiled As[kci][row][quad], conflict-free 1024B reads.
//   Q/K: mfma(wf, df) -> D[h][t];  V: mfma(df, wf) -> D[t][h].
// K epilogue stores in half-fragment order for attn's contiguous kf loads.
__global__ __launch_bounds__(768, 3) void qkv(const float* data, const bf16* __restrict__ Wp,
                                              bf16* arena, int regsz) {
  __shared__ bf16 As[64 * 1024];  // 128 KiB, tiled addressing via bytes
  char* As_b = (char*)As;
  int blk = blockIdx.x;
  int tid = threadIdx.x;
  int w = tid >> 6, lane = tid & 63;
  int l15 = lane & 15, quad = lane >> 4;

  // ---- stage 64 rows x 1024 f32 -> bf16 LDS (nontemporal, full coverage) --
  const float* src = data + (size_t)blk * 64 * C_SZ;
#pragma unroll
  for (int g = 0; g < 3; ++g) {
    f32x4 st[7];
#pragma unroll
    for (int i = 0; i < 7; ++i) {
      int u = (g * 7 + i) * 768 + tid;  // u < 16128 = rows 0..62
      st[i] = __builtin_nontemporal_load(
          (const f32x4*)(src + (size_t)(u >> 8) * C_SZ + (u & 255) * 4));
    }
#pragma unroll
    for (int i = 0; i < 7; ++i) {
      int u = (g * 7 + i) * 768 + tid;
      int row = u >> 8, c4 = u & 255;
      bf16 t4[4] = {(bf16)st[i][0], (bf16)st[i][1], (bf16)st[i][2], (bf16)st[i][3]};
      int bo = ((c4 >> 3) << 12) + row * 64 + (c4 & 7) * 8;
      *(u32x2*)(As_b + bo) = *(const u32x2*)t4;
    }
  }
  if (tid < 256) {  // tail: row 63
    int c4 = tid;
    f32x4 x = __builtin_nontemporal_load(
        (const f32x4*)(src + (size_t)63 * C_SZ + c4 * 4));
    bf16 t4[4] = {(bf16)x[0], (bf16)x[1], (bf16)x[2], (bf16)x[3]};
    int bo = ((c4 >> 3) << 12) + 63 * 64 + (c4 & 7) * 8;
    *(u32x2*)(As_b + bo) = *(const u32x2*)t4;
  }
  __syncthreads();

  // ---- compute: wave w owns fragment-col j = w ---------------------------
  int j = w;
  const bf16* wb = Wp + (size_t)j * 32 * 512 + l15 * 32 + quad * 8;  // kci stride 512
  bf16x8 wf[2];
  wf[0] = ld8(wb);        // kci 0
  wf[1] = ld8(wb + 512);  // kci 1

  f32x4 acc[4];
  f32x4 zero = {0.f, 0.f, 0.f, 0.f};
#pragma unroll
  for (int rg = 0; rg < 4; ++rg) acc[rg] = zero;

  bool isQK = (j < 8);
  int lbase = l15 * 64 + quad * 16;  // lane offset within a 1024B (kci,rg) slab

#pragma unroll 2
  for (int kci = 0; kci < 32; ++kci) {
    int cur = kci & 1;  // compile-time under unroll 2
    bf16x8 df[4];
#pragma unroll
    for (int rg = 0; rg < 4; ++rg) {
      int bo = (kci << 12) + rg * 1024 + lbase;
      df[rg] = ld8((const bf16*)(As_b + bo));
    }
    if (isQK) {
#pragma unroll
      for (int rg = 0; rg < 4; ++rg)
        acc[rg] = __builtin_amdgcn_mfma_f32_16x16x32_bf16(wf[cur], df[rg], acc[rg], 0, 0, 0);
    } else {
#pragma unroll
      for (int rg = 0; rg < 4; ++rg)
        acc[rg] = __builtin_amdgcn_mfma_f32_16x16x32_bf16(df[rg], wf[cur], acc[rg], 0, 0, 0);
    }
    wf[cur] = ld8(wb + ((kci + 2) & 31) * 512);  // refill for kci+2 (wrap-safe)
  }

  // ---- epilogue: packed 8B stores into 4 sub-regions ---------------------
#pragma unroll
  for (int rg = 0; rg < 4; ++rg) {
    bf16* reg = arena + (size_t)(blk * 4 + rg) * (size_t)regsz;
    bf16 p4[4] = {(bf16)acc[rg][0], (bf16)acc[rg][1], (bf16)acc[rg][2], (bf16)acc[rg][3]};
    if (j < 4) {         // Q: [t][h], t=l15, h = j*16 + quad*4 + r
      bf16* dst = reg + QOFF + l15 * 64 + j * 16 + quad * 4;
      *(u32x2*)dst = *(const u32x2*)p4;
    } else if (j < 8) {  // K: half-fragment order, h = (j-4)*16 + quad*4 + r
      int jk = j - 4;
      bf16* dst = reg + KOFF + (jk >> 1) * 512 + l15 * 32 + (jk & 1) * 16 + quad * 4;
      *(u32x2*)dst = *(const u32x2*)p4;
    } else {             // V: D[t][h] -> V^T[h][t16], h = (j-8)*16 + l15
      bf16* dst = reg + VOFF + ((j - 8) * 16 + l15) * 16 + quad * 4;
      *(u32x2*)dst = *(const u32x2*)p4;
    }
  }
}

// ---------------------------------------------------------------------------
// Flash attention, 32-q-rows/wave. Block = (qt, sp, b): q-rows qt*64+sp*32 ..
// +32 (slices A = qt*4+sp*2, B = +1). 4 waves own kt-QUARTERS with private
// (m,l,acc) per slice; one LDS merge at end. Each loaded K/V tile now feeds
// TWO 16-row QK/PV passes -> half the L2 traffic of the 16-row version.
// Next tile's K loads into the SAME kf regs right after QK (free prefetch,
// hidden under softmax+PV). Grid 512 1-D: b = id&7 (XCD pin), u = id>>3,
// sp = u&1, qt = u<32 ? 31-(u>>1) : (u-32)>>1 (each CU's 2 blocks sum to
// exactly 33 tiles). launch_bounds(256,2): VGPR cap 256 (est ~190, no spill).
__global__ __launch_bounds__(256, 2) void attn(const bf16* __restrict__ arena,
                                               float* __restrict__ out, int regsz) {
  __shared__ bf16 Ps[4][16 * PPITCH];
  __shared__ f32x4 Mg[3][12][64];  // waves 1..3: accA[4], accB[4], mA,lA,mB,lB
  int id = blockIdx.x;
  int b = id & 7;
  int u = id >> 3;
  int sp = u & 1;
  int qt = (u < 32) ? (31 - (u >> 1)) : ((u - 32) >> 1);
  int tid = threadIdx.x;
  int w = tid >> 6, lane = tid & 63;
  int l15 = lane & 15, quad = lane >> 4;

  const bf16* base = arena + (size_t)b * 128 * (size_t)regsz;

  const bf16* qregA = base + (size_t)(qt * 4 + sp * 2) * (size_t)regsz + QOFF + l15 * 64;
  const bf16* qregB = qregA + regsz;
  bf16x8 qfA0 = ld8(qregA + quad * 8), qfA1 = ld8(qregA + 32 + quad * 8);
  bf16x8 qfB0 = ld8(qregB + quad * 8), qfB1 = ld8(qregB + 32 + quad * 8);

  f32x4 accA[4], accB[4];
  f32x4 zero = {0.f, 0.f, 0.f, 0.f};
#pragma unroll
  for (int nt = 0; nt < 4; ++nt) { accA[nt] = zero; accB[nt] = zero; }
  float mA[4], lA[4], mB[4], lB[4];
#pragma unroll
  for (int r = 0; r < 4; ++r) { mA[r] = NEG_BIG; lA[r] = 0.f; mB[r] = NEG_BIG; lB[r] = 0.f; }

  int rowA = qt * 64 + sp * 32 + quad * 4;  // slice B rows = rowA + 16
  int vro = (quad >> 1);                    // V region sub-index
  int vco = (quad & 1) * 8;                 // V in-row offset

  // this wave's kt quarter
  int q4 = (qt + 4) >> 2;                // ceil((qt+1)/4)
  int kbeg = w * q4;
  int kend = min((w + 1) * q4, qt + 1);  // may be empty (kbeg >= kend)

  bf16x8 kf[8];
#pragma unroll
  for (int nt = 0; nt < 4; ++nt) {       // preload K for kt=kbeg (addr valid)
    const bf16* kp = base + (size_t)(kbeg * 4 + nt) * (size_t)regsz + KOFF + l15 * 32 + quad * 8;
    kf[2 * nt] = ld8(kp);
    kf[2 * nt + 1] = ld8(kp + 512);
  }

  for (int kt = kbeg; kt < kend; ++kt) {
    // V first half for this tile (shared by both slices; consumed in PV)
    bf16x8 vf0[4];
#pragma unroll
    for (int nt = 0; nt < 4; ++nt) {
      const bf16* vp = base + (size_t)(kt * 4 + vro) * (size_t)regsz + VOFF +
                       (nt * 16 + l15) * 16 + vco;
      vf0[nt] = ld8(vp);
    }

    // QK for both slices (kf dies here)
    f32x4 sA[4], sB[4];
#pragma unroll
    for (int nt = 0; nt < 4; ++nt) { sA[nt] = zero; sB[nt] = zero; }
#pragma unroll
    for (int nt = 0; nt < 4; ++nt) {
      sA[nt] = __builtin_amdgcn_mfma_f32_16x16x32_bf16(qfA0, kf[2 * nt], sA[nt], 0, 0, 0);
      sA[nt] = __builtin_amdgcn_mfma_f32_16x16x32_bf16(qfA1, kf[2 * nt + 1], sA[nt], 0, 0, 0);
    }
#pragma unroll
    for (int nt = 0; nt < 4; ++nt) {
      sB[nt] = __builtin_amdgcn_mfma_f32_16x16x32_bf16(qfB0, kf[2 * nt], sB[nt], 0, 0, 0);
      sB[nt] = __builtin_amdgcn_mfma_f32_16x16x32_bf16(qfB1, kf[2 * nt + 1], sB[nt], 0, 0, 0);
    }

    // free prefetch: next tile's K straight into kf (latency hides under
    // softmax+PV below); wave-uniform guard
    if (kt + 1 < kend) {
#pragma unroll
      for (int nt = 0; nt < 4; ++nt) {
        const bf16* kp = base + (size_t)((kt + 1) * 4 + nt) * (size_t)regsz + KOFF +
                         l15 * 32 + quad * 8;
        kf[2 * nt] = ld8(kp);
        kf[2 * nt + 1] = ld8(kp + 512);
      }
    }

    // V second half (consumed at end of PV; issue early)
    bf16x8 vf1[4];
#pragma unroll
    for (int nt = 0; nt < 4; ++nt) {
      const bf16* vp = base + (size_t)(kt * 4 + 2 + vro) * (size_t)regsz + VOFF +
                       (nt * 16 + l15) * 16 + vco;
      vf1[nt] = ld8(vp);
    }

    if (kt == qt) {  // causal mask on diagonal tile (both slices)
#pragma unroll
      for (int nt = 0; nt < 4; ++nt) {
        int colg = kt * 64 + nt * 16 + l15;
#pragma unroll
        for (int r = 0; r < 4; ++r) {
          if (colg > rowA + r) sA[nt][r] = NEG_BIG;
          if (colg > rowA + 16 + r) sB[nt][r] = NEG_BIG;
        }
      }
    }

    // online softmax, slice A then B
    float alA[4], alB[4];
#pragma unroll
    for (int r = 0; r < 4; ++r) {
      float mx = qmax16(fmaxf(fmaxf(sA[0][r], sA[1][r]), fmaxf(sA[2][r], sA[3][r])));
      float mnew = fmaxf(mA[r], mx);
      alA[r] = exp2f(mA[r] - mnew);
      mA[r] = mnew;
    }
#pragma unroll
    for (int r = 0; r < 4; ++r) {
      float mx = qmax16(fmaxf(fmaxf(sB[0][r], sB[1][r]), fmaxf(sB[2][r], sB[3][r])));
      float mnew = fmaxf(mB[r], mx);
      alB[r] = exp2f(mB[r] - mnew);
      mB[r] = mnew;
    }

    float rsA[4] = {0.f, 0.f, 0.f, 0.f}, rsB[4] = {0.f, 0.f, 0.f, 0.f};
#pragma unroll
    for (int nt = 0; nt < 4; ++nt) {
#pragma unroll
      for (int r = 0; r < 4; ++r) {
        float pA = exp2f(sA[nt][r] - mA[r]);
        sA[nt][r] = pA;
        rsA[r] += pA;
        float pB = exp2f(sB[nt][r] - mB[r]);
        sB[nt][r] = pB;
        rsB[r] += pB;
      }
    }
#pragma unroll
    for (int r = 0; r < 4; ++r) {
      lA[r] = lA[r] * alA[r] + qsum16(rsA[r]);
      lB[r] = lB[r] * alB[r] + qsum16(rsB[r]);
    }

    // ---- slice A: P transpose via per-wave LDS, then PV -------------------
#pragma unroll
    for (int nt = 0; nt < 4; ++nt)
#pragma unroll
      for (int r = 0; r < 4; ++r)
        Ps[w][(quad * 4 + r) * PPITCH + nt * 16 + l15] = (bf16)sA[nt][r];
#pragma unroll
    for (int nt = 0; nt < 4; ++nt)
#pragma unroll
      for (int r = 0; r < 4; ++r) accA[nt][r] *= alA[r];
    {
      bf16x8 pf0 = ld8((const bf16*)Ps[w] + l15 * PPITCH + quad * 8);
      bf16x8 pf1 = ld8((const bf16*)Ps[w] + l15 * PPITCH + 32 + quad * 8);
#pragma unroll
      for (int nt = 0; nt < 4; ++nt)
        accA[nt] = __builtin_amdgcn_mfma_f32_16x16x32_bf16(pf0, vf0[nt], accA[nt], 0, 0, 0);
#pragma unroll
      for (int nt = 0; nt < 4; ++nt)
        accA[nt] = __builtin_amdgcn_mfma_f32_16x16x32_bf16(pf1, vf1[nt], accA[nt], 0, 0, 0);
    }

    // ---- slice B: reuse the same Ps slice (same-wave RAW, in-order DS) ----
#pragma unroll
    for (int nt = 0; nt < 4; ++nt)
#pragma unroll
      for (int r = 0; r < 4; ++r)
        Ps[w][(quad * 4 + r) * PPITCH + nt * 16 + l15] = (bf16)sB[nt][r];
#pragma unroll
    for (int nt = 0; nt < 4; ++nt)
#pragma unroll
      for (int r = 0; r < 4; ++r) accB[nt][r] *= alB[r];
    {
      bf16x8 pf0 = ld8((const bf16*)Ps[w] + l15 * PPITCH + quad * 8);
      bf16x8 pf1 = ld8((const bf16*)Ps[w] + l15 * PPITCH + 32 + quad * 8);
#pragma unroll
      for (int nt = 0; nt < 4; ++nt)
        accB[nt] = __builtin_amdgcn_mfma_f32_16x16x32_bf16(pf0, vf0[nt], accB[nt], 0, 0, 0);
#pragma unroll
      for (int nt = 0; nt < 4; ++nt)
        accB[nt] = __builtin_amdgcn_mfma_f32_16x16x32_bf16(pf1, vf1[nt], accB[nt], 0, 0, 0);
    }
  }

  // merge the 4 kt-quarter partials (exact: O* = sum_w O_w * 2^(m_w - m*))
  if (w > 0) {
#pragma unroll
    for (int nt = 0; nt < 4; ++nt) {
      Mg[w - 1][nt][lane] = accA[nt];
      Mg[w - 1][4 + nt][lane] = accB[nt];
    }
    f32x4 v8 = {mA[0], mA[1], mA[2], mA[3]};
    f32x4 v9 = {lA[0], lA[1], lA[2], lA[3]};
    f32x4 v10 = {mB[0], mB[1], mB[2], mB[3]};
    f32x4 v11 = {lB[0], lB[1], lB[2], lB[3]};
    Mg[w - 1][8][lane] = v8;
    Mg[w - 1][9][lane] = v9;
    Mg[w - 1][10][lane] = v10;
    Mg[w - 1][11][lane] = v11;
  }
  __syncthreads();
  if (w == 0) {
#pragma unroll
    for (int wv = 0; wv < 3; ++wv) {
      f32x4 moA = Mg[wv][8][lane], loA = Mg[wv][9][lane];
      f32x4 moB = Mg[wv][10][lane], loB = Mg[wv][11][lane];
#pragma unroll
      for (int r = 0; r < 4; ++r) {
        float mnew = fmaxf(mA[r], moA[r]);
        float a = exp2f(mA[r] - mnew);
        float bs = exp2f(moA[r] - mnew);
        lA[r] = lA[r] * a + loA[r] * bs;
#pragma unroll
        for (int nt = 0; nt < 4; ++nt)
          accA[nt][r] = accA[nt][r] * a + Mg[wv][nt][lane][r] * bs;
        mA[r] = mnew;
      }
#pragma unroll
      for (int r = 0; r < 4; ++r) {
        float mnew = fmaxf(mB[r], moB[r]);
        float a = exp2f(mB[r] - mnew);
        float bs = exp2f(moB[r] - mnew);
        lB[r] = lB[r] * a + loB[r] * bs;
#pragma unroll
        for (int nt = 0; nt < 4; ++nt)
          accB[nt][r] = accB[nt][r] * a + Mg[wv][4 + nt][lane][r] * bs;
        mB[r] = mnew;
      }
    }

    float invA[4], invB[4];
#pragma unroll
    for (int r = 0; r < 4; ++r) { invA[r] = 1.f / lA[r]; invB[r] = 1.f / lB[r]; }
#pragma unroll
    for (int nt = 0; nt < 4; ++nt) {
#pragma unroll
      for (int r = 0; r < 4; ++r) {
        int tA = qt * 64 + sp * 32 + quad * 4 + r;
        int h = nt * 16 + l15;
        out[((size_t)b * T_SZ + tA) * H_SZ + h] = accA[nt][r] * invA[r];
        out[((size_t)b * T_SZ + tA + 16) * H_SZ + h] = accB[nt][r] * invB[r];
      }
    }
  }
}

// ---------------------------------------------------------------------------
extern "C" void kernel_launch(void* const* d_in, const int* in_sizes, int n_in,
                              void* d_out, int out_size, void* d_ws, size_t ws_size,
                              hipStream_t stream) {
  const float* data = (const float*)d_in[0];

  // Preferred: arena (1024 regions x 4096 bf16 = 8 MB) + Wp (384 KB) in d_ws.
  // Fallback (tiny ws): alias input (stride 32768) + Wp in d_out. Each M=64
  // qkv block fully consumes its own 256 KB input before writing it.
  const size_t arena_bytes = (size_t)1024 * 4096 * sizeof(bf16);  // 8 MB
  const size_t wt_bytes = (size_t)3 * H_SZ * C_SZ * sizeof(bf16); // 384 KB
  bool ws_ok = (d_ws != nullptr) && (ws_size >= arena_bytes + wt_bytes);

  bf16* arena = ws_ok ? (bf16*)d_ws : (bf16*)d_in[0];
  bf16* Wp = ws_ok ? (bf16*)((char*)d_ws + arena_bytes) : (bf16*)d_out;
  int regsz = ws_ok ? 4096 : 32768;

  transpose_w<<<dim3(16, 3), 256, 0, stream>>>((const float*)d_in[1],
                                               (const float*)d_in[2],
                                               (const float*)d_in[3], Wp);
  qkv<<<256, 768, 0, stream>>>(data, Wp, arena, regsz);
  attn<<<512, 256, 0, stream>>>(arena, (float*)d_out, regsz);
}

// Round 13
// 129.870 us; speedup vs baseline: 1.0384x; 1.0194x over previous
//
#include <hip/hip_runtime.h>
#include <hip/hip_bf16.h>

// B=8, T=2048, C=1024, H=64 single-head causal attention. f32 in, f32 out.
// Round 22: byte-for-byte revert to the R18/R9 configuration — the best
// measured (130.05us). Post-R9 attempts all regressed or were neutral:
// qkv overlap family (R5 TLP, R7 row-dbuf, R10 col-chunks, R11 2-blk/CU)
// and attn traffic-halving (R12, falsified "attn is L2-BW-bound").
// Fixed budget: ~83us unconditional harness ws-poison fills + ~2us
// transpose + ~22us qkv + ~21us attn. Remaining gaps are protected by the
// barrier-lockstep structure (qkv) and the softmax/P-transpose serial chain
// (attn); both resisted direct attack.
// Key wins embedded here: fragment-order packed weights (Wp — every wf load
// is one contiguous 1KB block; R9's -13us), K stored as contiguous 1KB
// half-fragments for attn, tiled conflict-free LDS, 12-wave/1-blk-CU qkv
// with Wp read exactly once per CU, attn 4-way kt-split with private
// online-softmax state + LDS merge, b<->XCD pinning, LPT dispatch.
// Region map: region rt (0..1023) = 16 tokens, stride regsz bf16.
// Q[t][h]@0, K packed@1024 (2 half-frags), V^T[h][t16]@2048.

typedef __bf16 bf16;
typedef __bf16 bf16x8 __attribute__((ext_vector_type(8)));
typedef float f32x4 __attribute__((ext_vector_type(4)));
typedef unsigned int u32;
typedef u32 u32x2 __attribute__((ext_vector_type(2)));
typedef u32 u32x4 __attribute__((ext_vector_type(4)));

#define T_SZ 2048
#define C_SZ 1024
#define H_SZ 64
#define QOFF 0
#define KOFF 1024
#define VOFF 2048
#define PPITCH 72
#define NEG_BIG (-30000.0f)
#define QSCALE 0.04508422f  // (1/32) * log2(e)

__device__ __forceinline__ bf16x8 ld8(const bf16* p) { return *(const bf16x8*)p; }

// DPP rotate within 16-lane row. ROW_ROR:n = 0x120|n.
template <int CTRL>
__device__ __forceinline__ float dpp_mov(float x) {
  return __builtin_bit_cast(float,
      __builtin_amdgcn_update_dpp(0, __builtin_bit_cast(int, x), CTRL, 0xf, 0xf, true));
}
__device__ __forceinline__ float qmax16(float x) {
  x = fmaxf(x, dpp_mov<0x121>(x));
  x = fmaxf(x, dpp_mov<0x122>(x));
  x = fmaxf(x, dpp_mov<0x124>(x));
  x = fmaxf(x, dpp_mov<0x128>(x));
  return x;
}
__device__ __forceinline__ float qsum16(float x) {
  x += dpp_mov<0x121>(x);
  x += dpp_mov<0x122>(x);
  x += dpp_mov<0x124>(x);
  x += dpp_mov<0x128>(x);
  return x;
}

// ---------------------------------------------------------------------------
// Fragment-packed weights: Wp elem[(jj*32+kci)*512 + l15*32 + quad*8 + e] =
// W[c = kci*32+quad*8+e][h = (jj&3)*16+l15] of matrix jj>>2 (0=Q,1=K,2=V).
// QSCALE folded into Wq. Thread (r=h, cb) covers c = ct*64+cb .. +15.
__global__ __launch_bounds__(256) void transpose_w(const float* __restrict__ Wq,
                                                   const float* __restrict__ Wk,
                                                   const float* __restrict__ Wv,
                                                   bf16* __restrict__ Wp) {
  __shared__ float sh[64][65];
  int ct = blockIdx.x;
  int mat = blockIdx.y;
  const float* W = (mat == 0) ? Wq : (mat == 1 ? Wk : Wv);
  int tid = threadIdx.x;
  int r = tid >> 2, cb = (tid & 3) * 16;

  const f32x4* src = (const f32x4*)(W + (size_t)(ct * 64 + r) * H_SZ + cb);
#pragma unroll
  for (int v = 0; v < 4; ++v) {
    f32x4 x = src[v];
#pragma unroll
    for (int jx = 0; jx < 4; ++jx) sh[r][cb + v * 4 + jx] = x[jx];
  }
  __syncthreads();

  float scale = (mat == 0) ? QSCALE : 1.0f;
  bf16x8 o0, o1;
#pragma unroll
  for (int jx = 0; jx < 8; ++jx) o0[jx] = (bf16)(sh[cb + jx][r] * scale);
#pragma unroll
  for (int jx = 0; jx < 8; ++jx) o1[jx] = (bf16)(sh[cb + 8 + jx][r] * scale);

  int jj = mat * 4 + (r >> 4);       // fragment-col 0..11
  int l15 = r & 15;
  int c0 = ct * 64 + cb;
  int kci = c0 >> 5;
  int qa = (c0 >> 3) & 3;            // first quad of the 16-elem span
  bf16* dst = Wp + (size_t)(jj * 32 + kci) * 512 + l15 * 32 + qa * 8;
  *(bf16x8*)dst = o0;        // quad qa   (8 elems)
  *(bf16x8*)(dst + 8) = o1;  // quad qa+1 (8 elems)
}

// ---------------------------------------------------------------------------
// QKV: 256 blocks x 768 thr (12 waves), 1 block/CU, M=64 tokens.
// Wave j (0..11) owns ONE 16-col fragment (j<4 Q, j<8 K, else V) and feeds
// it to 4 MFMAs (row-groups) per kci. Wp traffic 384 KB/CU, every wf load
// contiguous 1KB. LDS: tiled As[kci][row][quad], conflict-free 1024B reads.
//   Q/K: mfma(wf, df) -> D[h][t];  V: mfma(df, wf) -> D[t][h].
// K epilogue stores in half-fragment order for attn's contiguous kf loads.
__global__ __launch_bounds__(768, 3) void qkv(const float* data, const bf16* __restrict__ Wp,
                                              bf16* arena, int regsz) {
  __shared__ bf16 As[64 * 1024];  // 128 KiB, tiled addressing via bytes
  char* As_b = (char*)As;
  int blk = blockIdx.x;
  int tid = threadIdx.x;
  int w = tid >> 6, lane = tid & 63;
  int l15 = lane & 15, quad = lane >> 4;

  // ---- stage 64 rows x 1024 f32 -> bf16 LDS (nontemporal, full coverage) --
  const float* src = data + (size_t)blk * 64 * C_SZ;
#pragma unroll
  for (int g = 0; g < 3; ++g) {
    f32x4 st[7];
#pragma unroll
    for (int i = 0; i < 7; ++i) {
      int u = (g * 7 + i) * 768 + tid;  // u < 16128 = rows 0..62
      st[i] = __builtin_nontemporal_load(
          (const f32x4*)(src + (size_t)(u >> 8) * C_SZ + (u & 255) * 4));
    }
#pragma unroll
    for (int i = 0; i < 7; ++i) {
      int u = (g * 7 + i) * 768 + tid;
      int row = u >> 8, c4 = u & 255;
      bf16 t4[4] = {(bf16)st[i][0], (bf16)st[i][1], (bf16)st[i][2], (bf16)st[i][3]};
      int bo = ((c4 >> 3) << 12) + row * 64 + (c4 & 7) * 8;
      *(u32x2*)(As_b + bo) = *(const u32x2*)t4;
    }
  }
  if (tid < 256) {  // tail: row 63
    int c4 = tid;
    f32x4 x = __builtin_nontemporal_load(
        (const f32x4*)(src + (size_t)63 * C_SZ + c4 * 4));
    bf16 t4[4] = {(bf16)x[0], (bf16)x[1], (bf16)x[2], (bf16)x[3]};
    int bo = ((c4 >> 3) << 12) + 63 * 64 + (c4 & 7) * 8;
    *(u32x2*)(As_b + bo) = *(const u32x2*)t4;
  }
  __syncthreads();

  // ---- compute: wave w owns fragment-col j = w ---------------------------
  int j = w;
  const bf16* wb = Wp + (size_t)j * 32 * 512 + l15 * 32 + quad * 8;  // kci stride 512
  bf16x8 wf[2];
  wf[0] = ld8(wb);        // kci 0
  wf[1] = ld8(wb + 512);  // kci 1

  f32x4 acc[4];
  f32x4 zero = {0.f, 0.f, 0.f, 0.f};
#pragma unroll
  for (int rg = 0; rg < 4; ++rg) acc[rg] = zero;

  bool isQK = (j < 8);
  int lbase = l15 * 64 + quad * 16;  // lane offset within a 1024B (kci,rg) slab

#pragma unroll 2
  for (int kci = 0; kci < 32; ++kci) {
    int cur = kci & 1;  // compile-time under unroll 2
    bf16x8 df[4];
#pragma unroll
    for (int rg = 0; rg < 4; ++rg) {
      int bo = (kci << 12) + rg * 1024 + lbase;
      df[rg] = ld8((const bf16*)(As_b + bo));
    }
    if (isQK) {
#pragma unroll
      for (int rg = 0; rg < 4; ++rg)
        acc[rg] = __builtin_amdgcn_mfma_f32_16x16x32_bf16(wf[cur], df[rg], acc[rg], 0, 0, 0);
    } else {
#pragma unroll
      for (int rg = 0; rg < 4; ++rg)
        acc[rg] = __builtin_amdgcn_mfma_f32_16x16x32_bf16(df[rg], wf[cur], acc[rg], 0, 0, 0);
    }
    wf[cur] = ld8(wb + ((kci + 2) & 31) * 512);  // refill for kci+2 (wrap-safe)
  }

  // ---- epilogue: packed 8B stores into 4 sub-regions ---------------------
#pragma unroll
  for (int rg = 0; rg < 4; ++rg) {
    bf16* reg = arena + (size_t)(blk * 4 + rg) * (size_t)regsz;
    bf16 p4[4] = {(bf16)acc[rg][0], (bf16)acc[rg][1], (bf16)acc[rg][2], (bf16)acc[rg][3]};
    if (j < 4) {         // Q: [t][h], t=l15, h = j*16 + quad*4 + r
      bf16* dst = reg + QOFF + l15 * 64 + j * 16 + quad * 4;
      *(u32x2*)dst = *(const u32x2*)p4;
    } else if (j < 8) {  // K: half-fragment order, h = (j-4)*16 + quad*4 + r
      int jk = j - 4;
      bf16* dst = reg + KOFF + (jk >> 1) * 512 + l15 * 32 + (jk & 1) * 16 + quad * 4;
      *(u32x2*)dst = *(const u32x2*)p4;
    } else {             // V: D[t][h] -> V^T[h][t16], h = (j-8)*16 + l15
      bf16* dst = reg + VOFF + ((j - 8) * 16 + l15) * 16 + quad * 4;
      *(u32x2*)dst = *(const u32x2*)p4;
    }
  }
}

// ---------------------------------------------------------------------------
// Flash attention. Block = one (qt, slice, b) 16x64 output tile; 4 waves each
// own a QUARTER of kt in [0, qt], private (m,l,accO); one LDS merge at end.
// Grid 1024 1-D: b = id&7 (pins batch b to XCD b), t = id>>3, slice = t&3,
// qt = 31-(t>>2) (LPT order). 4 blocks/CU -> 16 waves/CU.
// K is stored in half-fragment order: kf loads are contiguous 1KB blocks.
__global__ __launch_bounds__(256, 4) void attn(const bf16* __restrict__ arena,
                                               float* __restrict__ out, int regsz) {
  __shared__ bf16 Ps[4][16 * PPITCH];
  __shared__ f32x4 Mg[3][6][64];  // waves 1..3 dump {accO[0..3], m, l}
  int id = blockIdx.x;
  int b = id & 7;
  int t = id >> 3;
  int slice = t & 3;
  int qt = 31 - (t >> 2);
  int tid = threadIdx.x;
  int w = tid >> 6, lane = tid & 63;
  int l15 = lane & 15, quad = lane >> 4;

  const bf16* base = arena + (size_t)b * 128 * (size_t)regsz;

  const bf16* qreg = base + (size_t)(qt * 4 + slice) * (size_t)regsz + QOFF + l15 * 64;
  bf16x8 qf0 = ld8(qreg + quad * 8);
  bf16x8 qf1 = ld8(qreg + 32 + quad * 8);

  f32x4 accO[4];
  f32x4 zero = {0.f, 0.f, 0.f, 0.f};
#pragma unroll
  for (int nt = 0; nt < 4; ++nt) accO[nt] = zero;
  float m[4], l[4];
#pragma unroll
  for (int r = 0; r < 4; ++r) { m[r] = NEG_BIG; l[r] = 0.f; }

  int qrow_base = qt * 64 + slice * 16 + quad * 4;
  int vro = (quad >> 1);                 // V region sub-index
  int vco = (quad & 1) * 8;              // V in-row offset

  // this wave's kt quarter
  int q4 = (qt + 4) >> 2;                // ceil((qt+1)/4)
  int kbeg = w * q4;
  int kend = min((w + 1) * q4, qt + 1);  // may be empty (kbeg >= kend)

  for (int kt = kbeg; kt < kend; ++kt) {
    // K fragments for this tile (contiguous 1KB half-fragments)
    bf16x8 kf[8];
#pragma unroll
    for (int nt = 0; nt < 4; ++nt) {
      const bf16* kp = base + (size_t)(kt * 4 + nt) * (size_t)regsz + KOFF + l15 * 32 + quad * 8;
      kf[2 * nt] = ld8(kp);            // h 0..31 half
      kf[2 * nt + 1] = ld8(kp + 512);  // h 32..63 half
    }

    f32x4 sA[4];
#pragma unroll
    for (int nt = 0; nt < 4; ++nt) sA[nt] = zero;
#pragma unroll
    for (int nt = 0; nt < 4; ++nt) {
      sA[nt] = __builtin_amdgcn_mfma_f32_16x16x32_bf16(qf0, kf[2 * nt], sA[nt], 0, 0, 0);
      sA[nt] = __builtin_amdgcn_mfma_f32_16x16x32_bf16(qf1, kf[2 * nt + 1], sA[nt], 0, 0, 0);
    }

    // first V half: issue under the softmax (kf regs die at the MFMAs above)
    bf16x8 vf0[4];
#pragma unroll
    for (int nt = 0; nt < 4; ++nt) {
      const bf16* vp = base + (size_t)(kt * 4 + vro) * (size_t)regsz + VOFF +
                       (nt * 16 + l15) * 16 + vco;
      vf0[nt] = ld8(vp);
    }

    if (kt == qt) {  // causal mask on diagonal tile
#pragma unroll
      for (int nt = 0; nt < 4; ++nt) {
        int colg = kt * 64 + nt * 16 + l15;
#pragma unroll
        for (int r = 0; r < 4; ++r)
          if (colg > qrow_base + r) sA[nt][r] = NEG_BIG;
      }
    }

    float alpha[4];
#pragma unroll
    for (int r = 0; r < 4; ++r) {
      float mx = qmax16(fmaxf(fmaxf(sA[0][r], sA[1][r]), fmaxf(sA[2][r], sA[3][r])));
      float mnew = fmaxf(m[r], mx);
      alpha[r] = exp2f(m[r] - mnew);
      m[r] = mnew;
    }

    float rs[4] = {0.f, 0.f, 0.f, 0.f};
#pragma unroll
    for (int nt = 0; nt < 4; ++nt) {
#pragma unroll
      for (int r = 0; r < 4; ++r) {
        float p = exp2f(sA[nt][r] - m[r]);
        sA[nt][r] = p;
        rs[r] += p;
      }
    }
#pragma unroll
    for (int r = 0; r < 4; ++r) l[r] = l[r] * alpha[r] + qsum16(rs[r]);

    // P: C/D layout -> per-wave LDS -> A layout (same-wave RAW, lgkm-ordered)
#pragma unroll
    for (int nt = 0; nt < 4; ++nt) {
#pragma unroll
      for (int r = 0; r < 4; ++r)
        Ps[w][(quad * 4 + r) * PPITCH + nt * 16 + l15] = (bf16)sA[nt][r];
    }

    // second V half: issue before PV so latency hides under first PV block
    bf16x8 vf1[4];
#pragma unroll
    for (int nt = 0; nt < 4; ++nt) {
      const bf16* vp = base + (size_t)(kt * 4 + 2 + vro) * (size_t)regsz + VOFF +
                       (nt * 16 + l15) * 16 + vco;
      vf1[nt] = ld8(vp);
    }

#pragma unroll
    for (int nt = 0; nt < 4; ++nt) {
#pragma unroll
      for (int r = 0; r < 4; ++r) accO[nt][r] *= alpha[r];
    }
    bf16x8 pf0 = ld8((const bf16*)Ps[w] + l15 * PPITCH + quad * 8);
    bf16x8 pf1 = ld8((const bf16*)Ps[w] + l15 * PPITCH + 32 + quad * 8);
#pragma unroll
    for (int nt = 0; nt < 4; ++nt)
      accO[nt] = __builtin_amdgcn_mfma_f32_16x16x32_bf16(pf0, vf0[nt], accO[nt], 0, 0, 0);
#pragma unroll
    for (int nt = 0; nt < 4; ++nt)
      accO[nt] = __builtin_amdgcn_mfma_f32_16x16x32_bf16(pf1, vf1[nt], accO[nt], 0, 0, 0);
  }

  // merge the 4 kt-quarter partials (exact: O* = sum_w O_w * 2^(m_w - m*))
  if (w > 0) {
#pragma unroll
    for (int nt = 0; nt < 4; ++nt) Mg[w - 1][nt][lane] = accO[nt];
    f32x4 mv = {m[0], m[1], m[2], m[3]};
    f32x4 lv = {l[0], l[1], l[2], l[3]};
    Mg[w - 1][4][lane] = mv;
    Mg[w - 1][5][lane] = lv;
  }
  __syncthreads();
  if (w == 0) {
#pragma unroll
    for (int wv = 0; wv < 3; ++wv) {
      f32x4 mo = Mg[wv][4][lane];
      f32x4 lo = Mg[wv][5][lane];
      f32x4 oo[4];
#pragma unroll
      for (int nt = 0; nt < 4; ++nt) oo[nt] = Mg[wv][nt][lane];
#pragma unroll
      for (int r = 0; r < 4; ++r) {
        float mnew = fmaxf(m[r], mo[r]);
        float a = exp2f(m[r] - mnew);
        float bs = exp2f(mo[r] - mnew);
        l[r] = l[r] * a + lo[r] * bs;
#pragma unroll
        for (int nt = 0; nt < 4; ++nt) accO[nt][r] = accO[nt][r] * a + oo[nt][r] * bs;
        m[r] = mnew;
      }
    }

    float inv[4];
#pragma unroll
    for (int r = 0; r < 4; ++r) inv[r] = 1.f / l[r];
#pragma unroll
    for (int nt = 0; nt < 4; ++nt) {
#pragma unroll
      for (int r = 0; r < 4; ++r) {
        int tk = qt * 64 + slice * 16 + quad * 4 + r;
        int h = nt * 16 + l15;
        out[((size_t)b * T_SZ + tk) * H_SZ + h] = accO[nt][r] * inv[r];
      }
    }
  }
}

// ---------------------------------------------------------------------------
extern "C" void kernel_launch(void* const* d_in, const int* in_sizes, int n_in,
                              void* d_out, int out_size, void* d_ws, size_t ws_size,
                              hipStream_t stream) {
  const float* data = (const float*)d_in[0];

  // Preferred: arena (1024 regions x 4096 bf16 = 8 MB) + Wp (384 KB) in d_ws.
  // Fallback (tiny ws): alias input (stride 32768) + Wp in d_out. Each M=64
  // qkv block fully consumes its own 256 KB input before writing it.
  const size_t arena_bytes = (size_t)1024 * 4096 * sizeof(bf16);  // 8 MB
  const size_t wt_bytes = (size_t)3 * H_SZ * C_SZ * sizeof(bf16); // 384 KB
  bool ws_ok = (d_ws != nullptr) && (ws_size >= arena_bytes + wt_bytes);

  bf16* arena = ws_ok ? (bf16*)d_ws : (bf16*)d_in[0];
  bf16* Wp = ws_ok ? (bf16*)((char*)d_ws + arena_bytes) : (bf16*)d_out;
  int regsz = ws_ok ? 4096 : 32768;

  transpose_w<<<dim3(16, 3), 256, 0, stream>>>((const float*)d_in[1],
                                               (const float*)d_in[2],
                                               (const float*)d_in[3], Wp);
  qkv<<<256, 768, 0, stream>>>(data, Wp, arena, regsz);
  attn<<<1024, 256, 0, stream>>>(arena, (float*)d_out, regsz);
}